// Round 11
// baseline (123.439 us; speedup 1.0000x reference)
//
#include <hip/hip_runtime.h>
#include <math.h>

#define EPS 1e-6f

constexpr int B_ = 32;
constexpr int T_ = 8192;
constexpr int F_ = 128;
constexpr int FH = F_ / 2;      // 64 float2 per timestep row
constexpr int C_ = 128;         // main chunk length per block
constexpr int W_ = 512;         // warmup window: a^512 ~ 2.4e-6 (abs E error)
constexpr int GPB  = T_ / C_;   // 64 chunks per batch row
constexpr int NBLK = B_ * GPB;  // 2048 blocks, 64 threads each = 8 waves/CU

// fast pow for strictly-positive base
__device__ __forceinline__ float fpow(float b, float e) {
    return exp2f(e * __log2f(b));
}

__global__ __launch_bounds__(64) void pcen_warmup(
    const float2* __restrict__ x2,
    const float2* __restrict__ state2,
    const float2* __restrict__ ls2,
    const float2* __restrict__ la2,
    const float2* __restrict__ ld2,
    const float2* __restrict__ lr2,
    float2* __restrict__ y2,
    float2* __restrict__ ns2)
{
    const int tid = threadIdx.x;            // 0..63 -> feature pair
    const int g   = blockIdx.x % GPB;
    const int b   = blockIdx.x / GPB;
    const int t0  = g * C_;

    const float2 lsv = ls2[tid];
    const float s0 = expf(lsv.x), s1 = expf(lsv.y);
    const float a0 = 1.f - s0,   a1 = 1.f - s1;

    const float2* xp = x2 + (size_t)b * T_ * FH + tid;

    // ---- carry reconstruction ----
    float c0, c1;
    int tstart;
    if (t0 <= W_) {
        // exact: run from t=0 starting at the true initial state
        tstart = 0;
        const float2 st = state2[(size_t)b * FH + tid];
        c0 = st.x; c1 = st.y;
    } else {
        // approximate: contributions older than W_ steps are < a^W ~ 2.4e-6
        tstart = t0 - W_;
        c0 = 0.f; c1 = 0.f;
    }

    // warmup: recurrence only (no y math). Loads are re-reads of lines the
    // preceding chunks' blocks are main-reading concurrently -> L2/L3 hot.
    #pragma unroll 16
    for (int t = tstart; t < t0; ++t) {
        const float2 xv = xp[(size_t)t * FH];
        c0 = fmaf(a0, c0, s0 * xv.x);
        c1 = fmaf(a1, c1, s1 * xv.y);
    }

    // ---- y parameters ----
    const float2 lav = la2[tid];
    const float2 ldv = ld2[tid];
    const float2 lrv = lr2[tid];
    const float na0 = -expf(lav.x), na1 = -expf(lav.y);
    const float d0 = expf(ldv.x),  d1 = expf(ldv.y);
    const float r0 = expf(lrv.x),  r1 = expf(lrv.y);
    const float dr0 = fpow(d0, r0), dr1 = fpow(d1, r1);

    // ---- main chunk: recurrence + y ----
    float2* yp = y2 + (size_t)b * T_ * FH + tid;

    #pragma unroll 8
    for (int t = t0; t < t0 + C_; ++t) {
        const float2 xv = xp[(size_t)t * FH];

        c0 = fmaf(a0, c0, s0 * xv.x);
        c1 = fmaf(a1, c1, s1 * xv.y);

        // u = x * (EPS+E)^(-alpha);  y = (u + delta)^r - delta^r
        const float u0 = xv.x * exp2f(na0 * __log2f(EPS + c0));
        const float u1 = xv.y * exp2f(na1 * __log2f(EPS + c1));

        float2 yv;
        yv.x = exp2f(r0 * __log2f(u0 + d0)) - dr0;
        yv.y = exp2f(r1 * __log2f(u1 + d1)) - dr1;

        yp[(size_t)t * FH] = yv;
    }

    // final state from the last chunk's carry
    if (g == GPB - 1) {
        float2 cs; cs.x = c0; cs.y = c1;
        ns2[(size_t)b * FH + tid] = cs;
    }
}

extern "C" void kernel_launch(void* const* d_in, const int* in_sizes, int n_in,
                              void* d_out, int out_size, void* d_ws, size_t ws_size,
                              hipStream_t stream)
{
    const float* x         = (const float*)d_in[0];
    const float* state     = (const float*)d_in[1];
    const float* log_s     = (const float*)d_in[2];
    const float* log_alpha = (const float*)d_in[3];
    const float* log_delta = (const float*)d_in[4];
    const float* log_r     = (const float*)d_in[5];

    float* y         = (float*)d_out;
    float* new_state = y + (size_t)B_ * T_ * F_;

    pcen_warmup<<<dim3(NBLK), dim3(64), 0, stream>>>(
        (const float2*)x, (const float2*)state,
        (const float2*)log_s, (const float2*)log_alpha,
        (const float2*)log_delta, (const float2*)log_r,
        (float2*)y, (float2*)new_state);
}

// Round 12
// 82.058 us; speedup vs baseline: 1.5043x; 1.5043x over previous
//
#include <hip/hip_runtime.h>
#include <math.h>

#define EPS 1e-6f

constexpr int B_ = 32;
constexpr int T_ = 8192;
constexpr int F_ = 128;
constexpr int FG = F_ / 4;    // 32 float4 feature-groups per row
constexpr int FH = F_ / 2;    // 64 float2 feature-pairs per row

// fast pow for strictly-positive base
__device__ __forceinline__ float fpow(float b, float e) {
    return exp2f(e * __log2f(b));
}

// -------- pass 1 (unchanged from round 5): per-chunk local sums --------
template<int NC>
__global__ __launch_bounds__(256) void pcen_pass1(
    const float4* __restrict__ x4,
    const float*  __restrict__ log_s,
    float4* __restrict__ S4)
{
    constexpr int L = T_ / NC;
    const int fg    = threadIdx.x & 31;
    const int slot  = threadIdx.x >> 5;              // 0..7
    const int cb    = blockIdx.x % (NC / 8);
    const int b     = blockIdx.x / (NC / 8);
    const int chunk = cb * 8 + slot;

    const float4 lsv = reinterpret_cast<const float4*>(log_s)[fg];
    const float s0 = expf(lsv.x), s1 = expf(lsv.y), s2 = expf(lsv.z), s3 = expf(lsv.w);
    const float a0 = 1.f - s0,   a1 = 1.f - s1,    a2 = 1.f - s2,    a3 = 1.f - s3;

    const float4* xp = x4 + ((size_t)b * T_ + (size_t)chunk * L) * FG + fg;

    float c0 = 0.f, c1 = 0.f, c2 = 0.f, c3 = 0.f;
    #pragma unroll
    for (int i = 0; i < L; ++i) {
        const float4 xv = xp[(size_t)i * FG];
        c0 = fmaf(a0, c0, s0 * xv.x);
        c1 = fmaf(a1, c1, s1 * xv.y);
        c2 = fmaf(a2, c2, s2 * xv.z);
        c3 = fmaf(a3, c3, s3 * xv.w);
    }
    S4[((size_t)b * NC + chunk) * FG + fg] = make_float4(c0, c1, c2, c3);
}

// -------- pass 2 (unchanged from round 5): serial combine -> carries --------
template<int NC>
__global__ __launch_bounds__(32) void pcen_pass2(
    const float4* __restrict__ state4,
    const float*  __restrict__ log_s,
    const float4* __restrict__ S4,
    float4* __restrict__ carry4,
    float4* __restrict__ new_state4)
{
    constexpr int L = T_ / NC;
    const int fg = threadIdx.x;   // 0..31
    const int b  = blockIdx.x;

    const float4 lsv = reinterpret_cast<const float4*>(log_s)[fg];
    const float aL0 = fpow(1.f - expf(lsv.x), (float)L);
    const float aL1 = fpow(1.f - expf(lsv.y), (float)L);
    const float aL2 = fpow(1.f - expf(lsv.z), (float)L);
    const float aL3 = fpow(1.f - expf(lsv.w), (float)L);

    float4 c = state4[(size_t)b * FG + fg];
    #pragma unroll 8
    for (int k = 0; k < NC; ++k) {
        const size_t idx = ((size_t)b * NC + k) * FG + fg;
        carry4[idx] = c;
        const float4 Sv = S4[idx];
        c.x = fmaf(aL0, c.x, Sv.x);
        c.y = fmaf(aL1, c.y, Sv.y);
        c.z = fmaf(aL2, c.z, Sv.z);
        c.w = fmaf(aL3, c.w, Sv.w);
    }
    new_state4[(size_t)b * FG + fg] = c;
}

// -------- pass 3 REWORKED: float2 threads, 2048 blocks, 4-deep batching --------
template<int NC>
__global__ __launch_bounds__(256) void pcen_pass3(
    const float2* __restrict__ x2,
    const float*  __restrict__ log_s,
    const float*  __restrict__ log_alpha,
    const float*  __restrict__ log_delta,
    const float*  __restrict__ log_r,
    const float2* __restrict__ carry2,
    float2* __restrict__ y2)
{
    constexpr int L = T_ / NC;            // 32
    const int lane  = threadIdx.x & 63;   // feature pair 0..63
    const int slot  = threadIdx.x >> 6;   // 0..3 chunk slot
    const int cb    = blockIdx.x % (NC / 4);
    const int b     = blockIdx.x / (NC / 4);
    const int chunk = cb * 4 + slot;

    const float2 lsv = reinterpret_cast<const float2*>(log_s)[lane];
    const float s0 = expf(lsv.x), s1 = expf(lsv.y);
    const float a0 = 1.f - s0,   a1 = 1.f - s1;

    const float2 lav = reinterpret_cast<const float2*>(log_alpha)[lane];
    const float2 ldv = reinterpret_cast<const float2*>(log_delta)[lane];
    const float2 lrv = reinterpret_cast<const float2*>(log_r)[lane];
    const float na0 = -expf(lav.x), na1 = -expf(lav.y);
    const float d0 = expf(ldv.x),  d1 = expf(ldv.y);
    const float r0 = expf(lrv.x),  r1 = expf(lrv.y);
    const float dr0 = fpow(d0, r0), dr1 = fpow(d1, r1);

    float2 c = carry2[((size_t)b * NC + chunk) * FH + lane];

    const size_t base = ((size_t)b * T_ + (size_t)chunk * L) * FH + lane;
    const float2* xp = x2 + base;
    float2*       yp = y2 + base;

    #pragma unroll
    for (int i = 0; i < L; i += 4) {
        // batch-load 4 timesteps (independent addresses -> 4 loads in flight)
        float2 xv0 = xp[(size_t)(i + 0) * FH];
        float2 xv1 = xp[(size_t)(i + 1) * FH];
        float2 xv2 = xp[(size_t)(i + 2) * FH];
        float2 xv3 = xp[(size_t)(i + 3) * FH];

        float2 yv0, yv1, yv2, yv3;

        c.x = fmaf(a0, c.x, s0 * xv0.x);
        c.y = fmaf(a1, c.y, s1 * xv0.y);
        yv0.x = exp2f(r0 * __log2f(xv0.x * exp2f(na0 * __log2f(EPS + c.x)) + d0)) - dr0;
        yv0.y = exp2f(r1 * __log2f(xv0.y * exp2f(na1 * __log2f(EPS + c.y)) + d1)) - dr1;

        c.x = fmaf(a0, c.x, s0 * xv1.x);
        c.y = fmaf(a1, c.y, s1 * xv1.y);
        yv1.x = exp2f(r0 * __log2f(xv1.x * exp2f(na0 * __log2f(EPS + c.x)) + d0)) - dr0;
        yv1.y = exp2f(r1 * __log2f(xv1.y * exp2f(na1 * __log2f(EPS + c.y)) + d1)) - dr1;

        c.x = fmaf(a0, c.x, s0 * xv2.x);
        c.y = fmaf(a1, c.y, s1 * xv2.y);
        yv2.x = exp2f(r0 * __log2f(xv2.x * exp2f(na0 * __log2f(EPS + c.x)) + d0)) - dr0;
        yv2.y = exp2f(r1 * __log2f(xv2.y * exp2f(na1 * __log2f(EPS + c.y)) + d1)) - dr1;

        c.x = fmaf(a0, c.x, s0 * xv3.x);
        c.y = fmaf(a1, c.y, s1 * xv3.y);
        yv3.x = exp2f(r0 * __log2f(xv3.x * exp2f(na0 * __log2f(EPS + c.x)) + d0)) - dr0;
        yv3.y = exp2f(r1 * __log2f(xv3.y * exp2f(na1 * __log2f(EPS + c.y)) + d1)) - dr1;

        yp[(size_t)(i + 0) * FH] = yv0;
        yp[(size_t)(i + 1) * FH] = yv1;
        yp[(size_t)(i + 2) * FH] = yv2;
        yp[(size_t)(i + 3) * FH] = yv3;
    }
}

template<int NC>
static void launch_all(const float* x, const float* state,
                       const float* log_s, const float* log_alpha,
                       const float* log_delta, const float* log_r,
                       float* y, float* new_state, float* ws, hipStream_t stream)
{
    const float4* x4      = (const float4*)x;
    const float4* state4  = (const float4*)state;
    float4* new_state4    = (float4*)new_state;
    float4* S4            = (float4*)ws;                 // B*NC*FG float4
    float4* carry4        = S4 + (size_t)B_ * NC * FG;   // B*NC*FG float4

    pcen_pass1<NC><<<dim3(B_ * (NC / 8)), dim3(256), 0, stream>>>(x4, log_s, S4);
    pcen_pass2<NC><<<dim3(B_), dim3(32), 0, stream>>>(state4, log_s, S4, carry4, new_state4);
    pcen_pass3<NC><<<dim3(B_ * (NC / 4)), dim3(256), 0, stream>>>(
        (const float2*)x, log_s, log_alpha, log_delta, log_r,
        (const float2*)carry4, (float2*)y);
}

extern "C" void kernel_launch(void* const* d_in, const int* in_sizes, int n_in,
                              void* d_out, int out_size, void* d_ws, size_t ws_size,
                              hipStream_t stream)
{
    const float* x         = (const float*)d_in[0];
    const float* state     = (const float*)d_in[1];
    const float* log_s     = (const float*)d_in[2];
    const float* log_alpha = (const float*)d_in[3];
    const float* log_delta = (const float*)d_in[4];
    const float* log_r     = (const float*)d_in[5];

    float* y         = (float*)d_out;
    float* new_state = y + (size_t)B_ * T_ * F_;

    // workspace need: 2 buffers of B*NC*F floats
    const size_t need256 = 2ull * B_ * 256 * F_ * sizeof(float);   // 8 MB
    const size_t need128 = 2ull * B_ * 128 * F_ * sizeof(float);   // 4 MB
    if (ws_size >= need256) {
        launch_all<256>(x, state, log_s, log_alpha, log_delta, log_r,
                        y, new_state, (float*)d_ws, stream);
    } else if (ws_size >= need128) {
        launch_all<128>(x, state, log_s, log_alpha, log_delta, log_r,
                        y, new_state, (float*)d_ws, stream);
    } else {
        launch_all<64>(x, state, log_s, log_alpha, log_delta, log_r,
                       y, new_state, (float*)d_ws, stream);
    }
}